// Round 3
// baseline (63.829 us; speedup 1.0000x reference)
//
#include <hip/hip_runtime.h>

typedef __bf16 bf16;
typedef __bf16 bf16x4 __attribute__((ext_vector_type(4)));
typedef __bf16 bf16x8 __attribute__((ext_vector_type(8)));
typedef float f32x4 __attribute__((ext_vector_type(4)));

#define SEQ 1024
#define EMB 1024
#define NH 16
#define HD 64
#define M2 2047   // 2*MAX_POS - 1

// ---------------------------------------------------------------------------
// Prep kernel: blocks 0..255  -> transpose W (f32 [k][n]) into Wt (bf16 [n][k])
//              blocks 256..1279 -> convert posEmb rows (clamped) to bf16 Ab[2048][1024]
// ---------------------------------------------------------------------------
__global__ __launch_bounds__(256) void prep_kernel(const float* __restrict__ posEmb,
                                                   const float* __restrict__ W,
                                                   bf16* __restrict__ Ab,
                                                   bf16* __restrict__ Wt) {
  const int tid = threadIdx.x;
  const int bx  = blockIdx.x;
  if (bx < 256) {
    __shared__ bf16 Tt[64][66];          // [n][k] tile, stride 66 vs conflicts
    const int k0 = (bx >> 4) * 64, n0 = (bx & 15) * 64;
    const int r = tid >> 2, cb = (tid & 3) * 16;
    const float4* src = reinterpret_cast<const float4*>(W + (size_t)(k0 + r) * EMB + n0 + cb);
    #pragma unroll
    for (int v = 0; v < 4; ++v) {
      float4 f = src[v];
      Tt[cb + v * 4 + 0][r] = (bf16)f.x;
      Tt[cb + v * 4 + 1][r] = (bf16)f.y;
      Tt[cb + v * 4 + 2][r] = (bf16)f.z;
      Tt[cb + v * 4 + 3][r] = (bf16)f.w;
    }
    __syncthreads();
    bf16* dst = Wt + (size_t)(n0 + r) * EMB + k0 + cb;
    bf16x8 o0, o1;
    #pragma unroll
    for (int i = 0; i < 8; ++i) { o0[i] = Tt[r][cb + i]; o1[i] = Tt[r][cb + 8 + i]; }
    *reinterpret_cast<bf16x8*>(dst)     = o0;
    *reinterpret_cast<bf16x8*>(dst + 8) = o1;
  } else {
    const int idx = (bx - 256) * 256 + tid;      // 0 .. 262143 (8 floats each)
    const int m = idx >> 7;
    const int c = (idx & 127) * 8;
    const int g = m > M2 - 1 ? M2 - 1 : m;
    const float4* s = reinterpret_cast<const float4*>(posEmb + (size_t)g * EMB + c);
    float4 v0 = s[0], v1 = s[1];
    bf16x8 o = { (bf16)v0.x, (bf16)v0.y, (bf16)v0.z, (bf16)v0.w,
                 (bf16)v1.x, (bf16)v1.y, (bf16)v1.z, (bf16)v1.w };
    *reinterpret_cast<bf16x8*>(Ab + (size_t)m * EMB + c) = o;
  }
}

// ---------------------------------------------------------------------------
// Kernel 1 (REWRITTEN): P[2048][1024] bf16 = Ab @ Wt^T, both operands bf16.
//   64x64 tile, BK=64, double-buffered global_load_lds(16B) staging with
//   XOR-swizzle (linear dest + pre-swizzled source + swizzled ds_read_b128).
// ---------------------------------------------------------------------------
__global__ __launch_bounds__(256) void gemm1b_kernel(const bf16* __restrict__ Ab,
                                                     const bf16* __restrict__ Wt,
                                                     bf16* __restrict__ P) {
  __shared__ bf16 As[2][64 * 64];
  __shared__ bf16 Bs[2][64 * 64];
  const int tid  = threadIdx.x;
  const int lane = tid & 63;
  const int wave = tid >> 6;
  const int wr = wave >> 1, wc = wave & 1;
  const int m0 = blockIdx.y * 64;
  const int n0 = blockIdx.x * 64;

  const char* AbB = reinterpret_cast<const char*>(Ab);
  const char* WtB = reinterpret_cast<const char*>(Wt);

  auto STAGE = [&](int bi, int k0) {
    #pragma unroll
    for (int i = 0; i < 2; ++i) {
      int s   = wave * 128 + i * 64 + lane;    // 16B chunk slot (linear dest)
      int row = s >> 3;
      int cs  = s & 7;
      int cd  = cs ^ (row & 7);                // pre-swizzled source chunk
      const void* ga = AbB + ((size_t)(m0 + row) * EMB + k0) * 2 + cd * 16;
      const void* gb = WtB + ((size_t)(n0 + row) * EMB + k0) * 2 + cd * 16;
      char* la = reinterpret_cast<char*>(&As[bi][0]) + s * 16;
      char* lb = reinterpret_cast<char*>(&Bs[bi][0]) + s * 16;
      __builtin_amdgcn_global_load_lds(
          (const __attribute__((address_space(1))) void*)ga,
          (__attribute__((address_space(3))) void*)la, 16, 0, 0);
      __builtin_amdgcn_global_load_lds(
          (const __attribute__((address_space(1))) void*)gb,
          (__attribute__((address_space(3))) void*)lb, 16, 0, 0);
    }
  };

  f32x4 acc[2][2] = {};

  STAGE(0, 0);
  __syncthreads();

  int cur = 0;
  for (int t = 0; t < 16; ++t) {
    if (t < 15) STAGE(cur ^ 1, (t + 1) * 64);

    const char* bufA = reinterpret_cast<const char*>(&As[cur][0]);
    const char* bufB = reinterpret_cast<const char*>(&Bs[cur][0]);
    #pragma unroll
    for (int ks = 0; ks < 2; ++ks) {
      bf16x8 a[2], b[2];
      #pragma unroll
      for (int x = 0; x < 2; ++x) {
        int ra = wr * 32 + x * 16 + (lane & 15);
        int rb = wc * 32 + x * 16 + (lane & 15);
        int ch = ks * 4 + (lane >> 4);
        a[x] = *reinterpret_cast<const bf16x8*>(bufA + ra * 128 + (ch ^ (ra & 7)) * 16);
        b[x] = *reinterpret_cast<const bf16x8*>(bufB + rb * 128 + (ch ^ (rb & 7)) * 16);
      }
      #pragma unroll
      for (int x = 0; x < 2; ++x)
        #pragma unroll
        for (int y = 0; y < 2; ++y)
          acc[x][y] = __builtin_amdgcn_mfma_f32_16x16x32_bf16(a[x], b[y], acc[x][y], 0, 0, 0);
    }
    __syncthreads();
    cur ^= 1;
  }

  #pragma unroll
  for (int x = 0; x < 2; ++x)
    #pragma unroll
    for (int y = 0; y < 2; ++y)
      #pragma unroll
      for (int r = 0; r < 4; ++r) {
        int row = m0 + wr * 32 + x * 16 + (lane >> 4) * 4 + r;
        int col = n0 + wc * 32 + y * 16 + (lane & 15);
        P[(size_t)row * EMB + col] = (bf16)acc[x][y][r];
      }
}

// ---------------------------------------------------------------------------
// Kernel 2 (UNCHANGED from round 2): band GEMM with m-loop inside the block.
// ---------------------------------------------------------------------------
__global__ __launch_bounds__(256) void band2_kernel(const float* __restrict__ q,
                                                    const bf16* __restrict__ P,
                                                    float* __restrict__ out) {
  __shared__ bf16 Pbuf[2][64 * 64];   // linear, swizzled content; 16 KB
  const int tid  = threadIdx.x;
  const int lane = tid & 63;
  const int wave = tid >> 6;
  const int wr = wave >> 1, wc = wave & 1;

  const int i0 = blockIdx.x * 64;
  const int hb = blockIdx.y;          // h*2 + b
  const int h  = hb >> 1;
  const int b  = hb & 1;

  bf16x8 a[2][2];
  {
    const float* qbase = q + ((size_t)(h * (2 * SEQ) + b * SEQ)) * HD;
    const int row = i0 + wr * 32 + (lane & 15);
    const int kof = 8 * (lane >> 4);
    #pragma unroll
    for (int x = 0; x < 2; ++x)
      #pragma unroll
      for (int ks = 0; ks < 2; ++ks) {
        const float* src = qbase + (size_t)(row + x * 16) * HD + ks * 32 + kof;
        float4 v0 = *reinterpret_cast<const float4*>(src);
        float4 v1 = *reinterpret_cast<const float4*>(src + 4);
        bf16x8 f = { (bf16)v0.x, (bf16)v0.y, (bf16)v0.z, (bf16)v0.w,
                     (bf16)v1.x, (bf16)v1.y, (bf16)v1.z, (bf16)v1.w };
        a[x][ks] = f;
      }
  }

  const int m_base = (SEQ - 1) - (i0 + 63);     // m for t=0 (>= 0)
  const int tb = blockIdx.z * 9;                // 0 or 9
  const int te = (blockIdx.z == 0) ? 9 : 17;    // 9 or 8 tiles

  auto STAGE = [&](int bi, int t) {
    const int m0 = m_base + t * 64;
    const char* Pb = reinterpret_cast<const char*>(P);
    #pragma unroll
    for (int i = 0; i < 2; ++i) {
      int s   = wave * 128 + i * 64 + lane;
      int row = s >> 3;
      int cs  = s & 7;
      int cd  = cs ^ (row & 7);
      const void* g = Pb + ((size_t)(m0 + row) * EMB + h * HD) * 2 + cd * 16;
      char* l = reinterpret_cast<char*>(&Pbuf[bi][0]) + (wave * 128 + i * 64) * 16;
      __builtin_amdgcn_global_load_lds(
          (const __attribute__((address_space(1))) void*)g,
          (__attribute__((address_space(3))) void*)l, 16, 0, 0);
    }
  };

  const size_t outbase = (size_t)hb << 20;      // hb * SEQ * SEQ

  STAGE(0, tb);
  __syncthreads();

  int cur = 0;
  for (int t = tb; t < te; ++t) {
    if (t + 1 < te) STAGE(cur ^ 1, t + 1);

    const char* buf = reinterpret_cast<const char*>(&Pbuf[cur][0]);
    f32x4 acc[2][2] = {};
    #pragma unroll
    for (int ks = 0; ks < 2; ++ks) {
      bf16x8 bb[2];
      #pragma unroll
      for (int y = 0; y < 2; ++y) {
        int mrow  = wc * 32 + y * 16 + (lane & 15);
        int chunk = ks * 4 + (lane >> 4);
        int sw    = chunk ^ (mrow & 7);
        bb[y] = *reinterpret_cast<const bf16x8*>(buf + mrow * 128 + sw * 16);
      }
      #pragma unroll
      for (int x = 0; x < 2; ++x)
        #pragma unroll
        for (int y = 0; y < 2; ++y)
          acc[x][y] = __builtin_amdgcn_mfma_f32_16x16x32_bf16(a[x][ks], bb[y], acc[x][y], 0, 0, 0);
    }

    const int m0 = m_base + t * 64;
    #pragma unroll
    for (int x = 0; x < 2; ++x)
      #pragma unroll
      for (int y = 0; y < 2; ++y)
        #pragma unroll
        for (int r = 0; r < 4; ++r) {
          int i = i0 + wr * 32 + x * 16 + (lane >> 4) * 4 + r;
          int m = m0 + wc * 32 + y * 16 + (lane & 15);
          int j = m - (SEQ - 1) + i;
          if ((unsigned)j < SEQ)
            out[outbase + (size_t)i * SEQ + j] = acc[x][y][r];
        }

    __syncthreads();
    cur ^= 1;
  }
}

extern "C" void kernel_launch(void* const* d_in, const int* in_sizes, int n_in,
                              void* d_out, int out_size, void* d_ws, size_t ws_size,
                              hipStream_t stream) {
  const float* query  = (const float*)d_in[0];   // [2,16,1024,64]
  const float* posEmb = (const float*)d_in[1];   // [2047,1024]
  const float* W      = (const float*)d_in[2];   // [1024,1024]
  float* out = (float*)d_out;                    // [2,16,1024,1024]

  char* ws = (char*)d_ws;
  bf16* P  = (bf16*)(ws);                        // 2048*1024*2 = 4 MB
  bf16* Ab = (bf16*)(ws + (4u << 20));           // 4 MB
  bf16* Wt = (bf16*)(ws + (8u << 20));           // 2 MB

  prep_kernel<<<1280, 256, 0, stream>>>(posEmb, W, Ab, Wt);
  gemm1b_kernel<<<dim3(16, 32), 256, 0, stream>>>(Ab, Wt, P);
  band2_kernel<<<dim3(16, 32, 2), 256, 0, stream>>>(query, P, out);
}